// Round 1
// baseline (4470.363 us; speedup 1.0000x reference)
//
#include <hip/hip_runtime.h>
#include <hip/hip_fp16.h>
#include <stdint.h>

// Problem constants
#define B_     16
#define T_     1000
#define F_     512
#define H_     512
#define NG_    1024     // 2H
#define M1_    16000    // B*T
#define STEPS_ 2000     // 2T

// ws layout (bytes)
#define WX_OFF     0            // __half[16000*1024] BN'd gates (wz | wh)      32,768,000 B
#define OUTPRE_OFF 32768000     // __half[16000*1024] hidden concat (pre-LN)    32,768,000 B
#define HTAG_OFF   65536000     // uint64_t[16 chains][2 parity][512]              131,072 B

__device__ __forceinline__ int swz(int c) { return c + ((c >> 5) & 3) * 4; }  // LDS bank swizzle

// ---------------------------------------------------------------------------
// init: reset tagged h buffers (h0 = 0, tag 0; parity-1 = sentinel), copy x_len
// ---------------------------------------------------------------------------
__global__ void init_kernel(uint64_t* __restrict__ htag, const int* __restrict__ xlen,
                            float* __restrict__ out_tail) {
    int i = blockIdx.x * 256 + threadIdx.x;
    if (i < B_ * 2 * H_) {
        uint64_t v = ((i >> 9) & 1) ? 0xFFFFFFFF00000000ULL : 0ULL; // parity1 sentinel / tag0+0.0f
        __hip_atomic_store(&htag[i], v, __ATOMIC_RELAXED, __HIP_MEMORY_SCOPE_AGENT);
    }
    if (i < B_) out_tail[i] = (float)xlen[i];
}

// ---------------------------------------------------------------------------
// Phase 1: WX[b,t,n] = BN(x[b,t,:] . W[n,:] + bias[n]),  n<512: Wz/z-params, else Wh/h-params
// 128x128 tile, K-tile 16, 256 threads, 8x8 micro-tile, fp32 compute, f16 store
// ---------------------------------------------------------------------------
__global__ __launch_bounds__(256) void gemm_gates(
    const float* __restrict__ x, const float* __restrict__ Wz, const float* __restrict__ Wh,
    const float* __restrict__ bz, const float* __restrict__ bh,
    const float* __restrict__ zg, const float* __restrict__ zb, const float* __restrict__ zm, const float* __restrict__ zv,
    const float* __restrict__ hg, const float* __restrict__ hb, const float* __restrict__ hm, const float* __restrict__ hv,
    __half* __restrict__ WX)
{
    __shared__ float As[16][132];
    __shared__ float Bs[16][144];
    int tid = threadIdx.x;
    int bm = blockIdx.x >> 3, bn = blockIdx.x & 7;
    int m0 = bm * 128, n0 = bn * 128;
    bool isZ = (n0 < 512);
    const float* Wsrc = isZ ? Wz : Wh;
    int nc0 = isZ ? n0 : (n0 - 512);
    const float* biasp = isZ ? bz : bh;
    const float* gp = isZ ? zg : hg;  const float* bp = isZ ? zb : hb;
    const float* mp = isZ ? zm : hm;  const float* vp = isZ ? zv : hv;
    int tm = tid >> 4, tn = tid & 15;
    float acc[8][8] = {};

    for (int k0 = 0; k0 < 512; k0 += 16) {
#pragma unroll
        for (int i = 0; i < 2; ++i) {
            int f = tid * 2 + i;
            int row = f >> 2, c4 = (f & 3) * 4;
            float4 v = *(const float4*)(x + (size_t)(m0 + row) * 512 + k0 + c4);
            As[c4 + 0][row] = v.x; As[c4 + 1][row] = v.y;
            As[c4 + 2][row] = v.z; As[c4 + 3][row] = v.w;
        }
#pragma unroll
        for (int i = 0; i < 2; ++i) {
            int f = tid * 2 + i;
            int row = f >> 2, c4 = (f & 3) * 4;
            float4 v = *(const float4*)(Wsrc + (size_t)(nc0 + row) * 512 + k0 + c4);
            int r = swz(row);
            Bs[c4 + 0][r] = v.x; Bs[c4 + 1][r] = v.y;
            Bs[c4 + 2][r] = v.z; Bs[c4 + 3][r] = v.w;
        }
        __syncthreads();
#pragma unroll
        for (int kk = 0; kk < 16; ++kk) {
            float a[8], b[8];
            *(float4*)&a[0] = *(const float4*)&As[kk][tm * 8];
            *(float4*)&a[4] = *(const float4*)&As[kk][tm * 8 + 4];
            *(float4*)&b[0] = *(const float4*)&Bs[kk][swz(tn * 8)];
            *(float4*)&b[4] = *(const float4*)&Bs[kk][swz(tn * 8) + 4];
#pragma unroll
            for (int i = 0; i < 8; ++i)
#pragma unroll
                for (int j = 0; j < 8; ++j)
                    acc[i][j] = fmaf(a[i], b[j], acc[i][j]);
        }
        __syncthreads();
    }

    float sc[8], sh[8];
#pragma unroll
    for (int j = 0; j < 8; ++j) {
        int nc = nc0 + tn * 8 + j;
        float s = gp[nc] * rsqrtf(vp[nc] + 1e-5f);
        sc[j] = s;
        sh[j] = (biasp[nc] - mp[nc]) * s + bp[nc];
    }
#pragma unroll
    for (int i = 0; i < 8; ++i) {
        size_t rowoff = (size_t)(m0 + tm * 8 + i) * NG_ + n0 + tn * 8;
#pragma unroll
        for (int j = 0; j < 4; ++j) {
            float v0 = acc[i][2 * j] * sc[2 * j] + sh[2 * j];
            float v1 = acc[i][2 * j + 1] * sc[2 * j + 1] + sh[2 * j + 1];
            *(__half2*)(WX + rowoff + 2 * j) = __floats2half2_rn(v0, v1);
        }
    }
}

// ---------------------------------------------------------------------------
// Phase 2: LiGRU recurrence. 16 chains x 16 WGs. WG g of chain c owns hidden
// cols j in [32g,32g+32). U slice (64 rows x 512) lives in registers.
// h exchanged via tagged u64 agent-scope atomics, parity double-buffered.
// ---------------------------------------------------------------------------
__global__ __launch_bounds__(256, 1) void recur_kernel(
    const __half* __restrict__ WX, const float* __restrict__ U,
    uint64_t* __restrict__ htag, __half* __restrict__ out_pre)
{
    int c = blockIdx.x & 15;     // chain (= forward batch)
    int g = blockIdx.x >> 4;     // column-group
    int tid = threadIdx.x;
    int lr = tid >> 2;           // local row 0..63 (row<32: Uz row 32g+lr, else Uh)
    int ck = tid & 3;            // 128-wide K chunk

    // Load U slice into registers (fixed for all 2000 steps)
    float ureg[128];
    {
        int urow = (lr < 32) ? (g * 32 + lr) : (H_ + g * 32 + (lr - 32));
        const float4* up = (const float4*)(U + (size_t)urow * H_ + ck * 128);
#pragma unroll
        for (int q = 0; q < 32; ++q) {
            float4 v = up[q];
            ureg[4 * q + 0] = v.x; ureg[4 * q + 1] = v.y;
            ureg[4 * q + 2] = v.z; ureg[4 * q + 3] = v.w;
        }
    }

    __shared__ float h_s[4 * 132];   // padded: chunk ck at offset ck*132
    __shared__ float u_s[64];

    uint64_t* myb = htag + (size_t)c * 1024;   // [2][512]
    int p0 = tid * 2, p1 = tid * 2 + 1;

    for (int t = 0; t < STEPS_; ++t) {
        // ---- poll h_t (tag == t) ----
        uint64_t* buf = myb + (size_t)(t & 1) * 512;
        uint32_t tag = (uint32_t)t;
        uint64_t v0 = __hip_atomic_load(&buf[p0], __ATOMIC_RELAXED, __HIP_MEMORY_SCOPE_AGENT);
        uint64_t v1 = __hip_atomic_load(&buf[p1], __ATOMIC_RELAXED, __HIP_MEMORY_SCOPE_AGENT);
        while ((uint32_t)(v0 >> 32) != tag) {
            __builtin_amdgcn_s_sleep(1);
            v0 = __hip_atomic_load(&buf[p0], __ATOMIC_RELAXED, __HIP_MEMORY_SCOPE_AGENT);
        }
        while ((uint32_t)(v1 >> 32) != tag) {
            __builtin_amdgcn_s_sleep(1);
            v1 = __hip_atomic_load(&buf[p1], __ATOMIC_RELAXED, __HIP_MEMORY_SCOPE_AGENT);
        }
        h_s[(p0 >> 7) * 132 + (p0 & 127)] = __uint_as_float((uint32_t)v0);
        h_s[(p1 >> 7) * 132 + (p1 & 127)] = __uint_as_float((uint32_t)v1);
        __syncthreads();   // h_s(t) complete

        // update-thread preloads (before anyone can overwrite h_s at t+1)
        float hold = 0.f, wzv = 0.f, whv = 0.f;
        if (tid < 32) {
            int j = g * 32 + tid;
            hold = h_s[(j >> 7) * 132 + (j & 127)];
            int sb = (t < T_) ? c : (B_ - 1 - c);
            int st = (t < T_) ? t : (t - T_);
            const __half* wrow = WX + (size_t)(sb * T_ + st) * NG_;
            wzv = __half2float(wrow[j]);
            whv = __half2float(wrow[H_ + j]);
        }

        // ---- u = h . U^T  (each thread: 1 row-chunk of 128) ----
        float acc = 0.f;
        const float4* h4 = (const float4*)(h_s + ck * 132);
#pragma unroll
        for (int q = 0; q < 32; ++q) {
            float4 hv = h4[q];
            acc = fmaf(ureg[4 * q + 0], hv.x, acc);
            acc = fmaf(ureg[4 * q + 1], hv.y, acc);
            acc = fmaf(ureg[4 * q + 2], hv.z, acc);
            acc = fmaf(ureg[4 * q + 3], hv.w, acc);
        }
        acc += __shfl_xor(acc, 1);
        acc += __shfl_xor(acc, 2);
        if (ck == 0) u_s[lr] = acc;
        __syncthreads();   // u_s complete; also fences h_s reads before next poll writes

        // ---- gate update + publish h_{t+1} ----
        if (tid < 32) {
            int j = g * 32 + tid;
            float uz = u_s[tid], uh = u_s[32 + tid];
            float z = 1.f / (1.f + __expf(-(wzv + uz)));
            float hc = fmaxf(whv + uh, 0.f);
            float hn = z * hold + (1.f - z) * hc;
            uint64_t pk = ((uint64_t)(uint32_t)(t + 1) << 32) | (uint64_t)__float_as_uint(hn);
            __hip_atomic_store(&myb[(size_t)((t + 1) & 1) * 512 + j], pk,
                               __ATOMIC_RELAXED, __HIP_MEMORY_SCOPE_AGENT);
            size_t off;
            if (t < T_) off = ((size_t)(c * T_ + t)) * NG_ + j;                       // forward half
            else        off = ((size_t)((B_ - 1 - c) * T_ + (t - T_))) * NG_ + H_ + j; // backward half
            out_pre[off] = __float2half(hn);
        }
    }
}

// ---------------------------------------------------------------------------
// Phase 3a: LayerNorm over last dim (1024), in place on f16 buffer
// ---------------------------------------------------------------------------
__global__ __launch_bounds__(256) void ln_kernel(__half* __restrict__ buf,
                                                 const float* __restrict__ g,
                                                 const float* __restrict__ b) {
    __shared__ float red[2][4];
    int row = blockIdx.x, tid = threadIdx.x;
    __half* p = buf + (size_t)row * NG_ + tid * 4;
    uint2 raw = *(const uint2*)p;
    __half2 h01 = *(__half2*)&raw.x, h23 = *(__half2*)&raw.y;
    float2 f01 = __half22float2(h01), f23 = __half22float2(h23);
    float s = f01.x + f01.y + f23.x + f23.y;
    float ss = fmaf(f01.x, f01.x, fmaf(f01.y, f01.y, fmaf(f23.x, f23.x, f23.y * f23.y)));
#pragma unroll
    for (int m = 32; m >= 1; m >>= 1) { s += __shfl_xor(s, m); ss += __shfl_xor(ss, m); }
    int w = tid >> 6;
    if ((tid & 63) == 0) { red[0][w] = s; red[1][w] = ss; }
    __syncthreads();
    float S = red[0][0] + red[0][1] + red[0][2] + red[0][3];
    float SS = red[1][0] + red[1][1] + red[1][2] + red[1][3];
    float mu = S * (1.f / NG_);
    float var = SS * (1.f / NG_) - mu * mu;
    float rstd = rsqrtf(var + 1e-5f);
    int d = tid * 4;
    float o0 = (f01.x - mu) * rstd * g[d + 0] + b[d + 0];
    float o1 = (f01.y - mu) * rstd * g[d + 1] + b[d + 1];
    float o2 = (f23.x - mu) * rstd * g[d + 2] + b[d + 2];
    float o3 = (f23.y - mu) * rstd * g[d + 3] + b[d + 3];
    __half2 a = __floats2half2_rn(o0, o1), c = __floats2half2_rn(o2, o3);
    uint2 out; out.x = *(uint32_t*)&a; out.y = *(uint32_t*)&c;
    *(uint2*)p = out;
}

// ---------------------------------------------------------------------------
// Phase 3b: projection GEMM: out[m,e] = tanh(LN[m,:] . pjW[e,:] + pjb[e]), fp32 out
// ---------------------------------------------------------------------------
__global__ __launch_bounds__(256) void gemm_proj(
    const __half* __restrict__ Ain, const float* __restrict__ pjW,
    const float* __restrict__ pjb, float* __restrict__ outp)
{
    __shared__ float As[16][132];
    __shared__ float Bs[16][144];
    int tid = threadIdx.x;
    int bm = blockIdx.x >> 3, bn = blockIdx.x & 7;
    int m0 = bm * 128, n0 = bn * 128;
    int tm = tid >> 4, tn = tid & 15;
    float acc[8][8] = {};

    for (int k0 = 0; k0 < 1024; k0 += 16) {
        {
            int row = tid >> 1, hb = (tid & 1) * 8;
            uint4 raw = *(const uint4*)(Ain + (size_t)(m0 + row) * NG_ + k0 + hb);
            const __half2* hp = (const __half2*)&raw;
#pragma unroll
            for (int q = 0; q < 4; ++q) {
                float2 f = __half22float2(hp[q]);
                As[hb + 2 * q][row] = f.x;
                As[hb + 2 * q + 1][row] = f.y;
            }
        }
#pragma unroll
        for (int i = 0; i < 2; ++i) {
            int f = tid * 2 + i;
            int row = f >> 2, c4 = (f & 3) * 4;
            float4 v = *(const float4*)(pjW + (size_t)(n0 + row) * 1024 + k0 + c4);
            int r = swz(row);
            Bs[c4 + 0][r] = v.x; Bs[c4 + 1][r] = v.y;
            Bs[c4 + 2][r] = v.z; Bs[c4 + 3][r] = v.w;
        }
        __syncthreads();
#pragma unroll
        for (int kk = 0; kk < 16; ++kk) {
            float a[8], b[8];
            *(float4*)&a[0] = *(const float4*)&As[kk][tm * 8];
            *(float4*)&a[4] = *(const float4*)&As[kk][tm * 8 + 4];
            *(float4*)&b[0] = *(const float4*)&Bs[kk][swz(tn * 8)];
            *(float4*)&b[4] = *(const float4*)&Bs[kk][swz(tn * 8) + 4];
#pragma unroll
            for (int i = 0; i < 8; ++i)
#pragma unroll
                for (int j = 0; j < 8; ++j)
                    acc[i][j] = fmaf(a[i], b[j], acc[i][j]);
        }
        __syncthreads();
    }

#pragma unroll
    for (int i = 0; i < 8; ++i) {
        size_t rowoff = (size_t)(m0 + tm * 8 + i) * NG_ + n0 + tn * 8;
#pragma unroll
        for (int j = 0; j < 8; ++j) {
            int n = n0 + tn * 8 + j;
            outp[rowoff + j] = tanhf(acc[i][j] + pjb[n]);
        }
    }
}

// ---------------------------------------------------------------------------
extern "C" void kernel_launch(void* const* d_in, const int* in_sizes, int n_in,
                              void* d_out, int out_size, void* d_ws, size_t ws_size,
                              hipStream_t stream) {
    const float* x    = (const float*)d_in[0];
    const int*   xlen = (const int*)  d_in[1];
    const float* Wz   = (const float*)d_in[2];
    const float* bz   = (const float*)d_in[3];
    const float* Wh   = (const float*)d_in[4];
    const float* bh   = (const float*)d_in[5];
    const float* U    = (const float*)d_in[6];
    const float* zg   = (const float*)d_in[7];
    const float* zb   = (const float*)d_in[8];
    const float* zm   = (const float*)d_in[9];
    const float* zv   = (const float*)d_in[10];
    const float* hg   = (const float*)d_in[11];
    const float* hb   = (const float*)d_in[12];
    const float* hm   = (const float*)d_in[13];
    const float* hv   = (const float*)d_in[14];
    const float* lng  = (const float*)d_in[15];
    const float* lnb  = (const float*)d_in[16];
    const float* pjW  = (const float*)d_in[17];
    const float* pjb  = (const float*)d_in[18];

    char* ws = (char*)d_ws;
    __half*   WX      = (__half*)(ws + WX_OFF);
    __half*   out_pre = (__half*)(ws + OUTPRE_OFF);
    uint64_t* htag    = (uint64_t*)(ws + HTAG_OFF);
    float* out = (float*)d_out;

    init_kernel<<<64, 256, 0, stream>>>(htag, xlen, out + (size_t)M1_ * NG_);
    gemm_gates<<<1000, 256, 0, stream>>>(x, Wz, Wh, bz, bh, zg, zb, zm, zv,
                                         hg, hb, hm, hv, WX);
    recur_kernel<<<256, 256, 0, stream>>>(WX, U, htag, out_pre);
    ln_kernel<<<M1_, 256, 0, stream>>>(out_pre, lng, lnb);
    gemm_proj<<<1000, 256, 0, stream>>>(out_pre, pjW, pjb, out);
}

// Round 2
// 3923.056 us; speedup vs baseline: 1.1395x; 1.1395x over previous
//
#include <hip/hip_runtime.h>
#include <hip/hip_fp16.h>
#include <stdint.h>

// Problem constants
#define B_     16
#define T_     1000
#define F_     512
#define H_     512
#define NG_    1024     // 2H
#define M1_    16000    // B*T
#define STEPS_ 2000     // 2T

// ws layout (bytes)
#define WX_OFF     0            // __half[16000*1024] BN'd gates (wz | wh)      32,768,000 B
#define OUTPRE_OFF 32768000     // __half[16000*1024] hidden concat (pre-LN)    32,768,000 B
#define HTAG_OFF   65536000     // uint64_t[16 chains][2 parity][512]              131,072 B

__device__ __forceinline__ int swz(int c) { return c + ((c >> 5) & 3) * 4; }  // LDS bank swizzle

typedef _Float16 h2_t __attribute__((ext_vector_type(2)));
union U32H2 { uint32_t u; h2_t h; };

__device__ __forceinline__ float dot2f(uint32_t a, uint32_t b, float c) {
#if __has_builtin(__builtin_amdgcn_fdot2)
    U32H2 ua, ub; ua.u = a; ub.u = b;
    return __builtin_amdgcn_fdot2(ua.h, ub.h, c, false);
#else
    __half2 ha = *(__half2*)&a, hb = *(__half2*)&b;
    float2 fa = __half22float2(ha), fb = __half22float2(hb);
    return fmaf(fa.x, fb.x, fmaf(fa.y, fb.y, c));
#endif
}

// ---------------------------------------------------------------------------
// init: reset tagged h buffers (h0 = 0, tag 0; parity-1 = sentinel), copy x_len
// ---------------------------------------------------------------------------
__global__ void init_kernel(uint64_t* __restrict__ htag, const int* __restrict__ xlen,
                            float* __restrict__ out_tail) {
    int i = blockIdx.x * 256 + threadIdx.x;
    if (i < B_ * 2 * H_) {
        uint64_t v = ((i >> 9) & 1) ? 0xFFFFFFFF00000000ULL : 0ULL; // parity1 sentinel / tag0+0.0f
        __hip_atomic_store(&htag[i], v, __ATOMIC_RELAXED, __HIP_MEMORY_SCOPE_AGENT);
    }
    if (i < B_) out_tail[i] = (float)xlen[i];
}

// ---------------------------------------------------------------------------
// Phase 1: WX[b,t,n] = BN(x[b,t,:] . W[n,:] + bias[n]),  n<512: Wz/z, else Wh/h
// 128x128 tile, K-tile 16, 256 threads, 8x8 micro-tile, fp32 compute, f16 store
// ---------------------------------------------------------------------------
__global__ __launch_bounds__(256) void gemm_gates(
    const float* __restrict__ x, const float* __restrict__ Wz, const float* __restrict__ Wh,
    const float* __restrict__ bz, const float* __restrict__ bh,
    const float* __restrict__ zg, const float* __restrict__ zb, const float* __restrict__ zm, const float* __restrict__ zv,
    const float* __restrict__ hg, const float* __restrict__ hb, const float* __restrict__ hm, const float* __restrict__ hv,
    __half* __restrict__ WX)
{
    __shared__ float As[16][132];
    __shared__ float Bs[16][144];
    int tid = threadIdx.x;
    int bm = blockIdx.x >> 3, bn = blockIdx.x & 7;
    int m0 = bm * 128, n0 = bn * 128;
    bool isZ = (n0 < 512);
    const float* Wsrc = isZ ? Wz : Wh;
    int nc0 = isZ ? n0 : (n0 - 512);
    const float* biasp = isZ ? bz : bh;
    const float* gp = isZ ? zg : hg;  const float* bp = isZ ? zb : hb;
    const float* mp = isZ ? zm : hm;  const float* vp = isZ ? zv : hv;
    int tm = tid >> 4, tn = tid & 15;
    float acc[8][8] = {};

    for (int k0 = 0; k0 < 512; k0 += 16) {
#pragma unroll
        for (int i = 0; i < 2; ++i) {
            int f = tid * 2 + i;
            int row = f >> 2, c4 = (f & 3) * 4;
            float4 v = *(const float4*)(x + (size_t)(m0 + row) * 512 + k0 + c4);
            As[c4 + 0][row] = v.x; As[c4 + 1][row] = v.y;
            As[c4 + 2][row] = v.z; As[c4 + 3][row] = v.w;
        }
#pragma unroll
        for (int i = 0; i < 2; ++i) {
            int f = tid * 2 + i;
            int row = f >> 2, c4 = (f & 3) * 4;
            float4 v = *(const float4*)(Wsrc + (size_t)(nc0 + row) * 512 + k0 + c4);
            int r = swz(row);
            Bs[c4 + 0][r] = v.x; Bs[c4 + 1][r] = v.y;
            Bs[c4 + 2][r] = v.z; Bs[c4 + 3][r] = v.w;
        }
        __syncthreads();
#pragma unroll
        for (int kk = 0; kk < 16; ++kk) {
            float a[8], b[8];
            *(float4*)&a[0] = *(const float4*)&As[kk][tm * 8];
            *(float4*)&a[4] = *(const float4*)&As[kk][tm * 8 + 4];
            *(float4*)&b[0] = *(const float4*)&Bs[kk][swz(tn * 8)];
            *(float4*)&b[4] = *(const float4*)&Bs[kk][swz(tn * 8) + 4];
#pragma unroll
            for (int i = 0; i < 8; ++i)
#pragma unroll
                for (int j = 0; j < 8; ++j)
                    acc[i][j] = fmaf(a[i], b[j], acc[i][j]);
        }
        __syncthreads();
    }

    float sc[8], sh[8];
#pragma unroll
    for (int j = 0; j < 8; ++j) {
        int nc = nc0 + tn * 8 + j;
        float s = gp[nc] * rsqrtf(vp[nc] + 1e-5f);
        sc[j] = s;
        sh[j] = (biasp[nc] - mp[nc]) * s + bp[nc];
    }
#pragma unroll
    for (int i = 0; i < 8; ++i) {
        size_t rowoff = (size_t)(m0 + tm * 8 + i) * NG_ + n0 + tn * 8;
#pragma unroll
        for (int j = 0; j < 4; ++j) {
            float v0 = acc[i][2 * j] * sc[2 * j] + sh[2 * j];
            float v1 = acc[i][2 * j + 1] * sc[2 * j + 1] + sh[2 * j + 1];
            *(__half2*)(WX + rowoff + 2 * j) = __floats2half2_rn(v0, v1);
        }
    }
}

// ---------------------------------------------------------------------------
// Phase 2: LiGRU recurrence. 16 chains x 16 WGs. WG g of chain c owns hidden
// cols j in [32g,32g+32). U slice (64 rows x 512) lives in registers as fp16x2;
// dot via v_dot2_f32_f16 (f32 accumulate). Recurrence STATE stays fp32 (u64
// tagged payload + fp32 side-array for hold).
// XCD-locality: blockIdx%8 selects the XCD (round-robin dispatch heuristic);
// all 16 WGs of a chain share blockIdx%8 so the h exchange stays in one L2.
// Mapping is a perf heuristic only — tags guarantee correctness regardless.
// ---------------------------------------------------------------------------
__global__ __launch_bounds__(256, 1) void recur_kernel(
    const __half* __restrict__ WX, const float* __restrict__ U,
    uint64_t* __restrict__ htag, __half* __restrict__ out_pre)
{
    int bI = blockIdx.x;
    int X  = bI & 7;          // target XCD
    int s  = bI >> 3;         // 0..31 within XCD residue class
    int c  = X * 2 + (s & 1); // chain
    int g  = s >> 1;          // column-group 0..15
    int tid = threadIdx.x;
    int lr = tid >> 2;        // local row 0..63 (row<32: Uz row 32g+lr, else Uh)
    int ck = tid & 3;         // 128-wide K chunk

    // Load U slice into registers as fp16x2 (fixed for all 2000 steps)
    uint32_t ureg[64];   // ureg[i] packs U[urow][ck*128+2i], U[urow][ck*128+2i+1]
    {
        int urow = (lr < 32) ? (g * 32 + lr) : (H_ + g * 32 + (lr - 32));
        const float4* up = (const float4*)(U + (size_t)urow * H_ + ck * 128);
#pragma unroll
        for (int q = 0; q < 32; ++q) {
            float4 v = up[q];
            __half2 a = __floats2half2_rn(v.x, v.y);
            __half2 b = __floats2half2_rn(v.z, v.w);
            ureg[2 * q]     = *(uint32_t*)&a;
            ureg[2 * q + 1] = *(uint32_t*)&b;
        }
    }

    // LDS: h as fp16, chunk ck at half-offset ck*136 (pad 8 halves -> banks
    // ck*4 apart, conflict-free reads; writes are 2 lanes/bank = free)
    __shared__ __align__(16) __half h_s[4 * 136];
    __shared__ float h32_s[32];   // fp32 h for this WG's own columns (state path)
    __shared__ float u_s[64];

    uint64_t* myb = htag + (size_t)c * 1024;   // [2][512]
    int p0 = tid * 2, p1 = tid * 2 + 1;

    for (int t = 0; t < STEPS_; ++t) {
        // ---- poll h_t (tag == t) ----
        uint64_t* buf = myb + (size_t)(t & 1) * 512;
        uint32_t tag = (uint32_t)t;
        uint64_t v0 = __hip_atomic_load(&buf[p0], __ATOMIC_RELAXED, __HIP_MEMORY_SCOPE_AGENT);
        uint64_t v1 = __hip_atomic_load(&buf[p1], __ATOMIC_RELAXED, __HIP_MEMORY_SCOPE_AGENT);
        while ((uint32_t)(v0 >> 32) != tag) {
            __builtin_amdgcn_s_sleep(1);
            v0 = __hip_atomic_load(&buf[p0], __ATOMIC_RELAXED, __HIP_MEMORY_SCOPE_AGENT);
        }
        while ((uint32_t)(v1 >> 32) != tag) {
            __builtin_amdgcn_s_sleep(1);
            v1 = __hip_atomic_load(&buf[p1], __ATOMIC_RELAXED, __HIP_MEMORY_SCOPE_AGENT);
        }
        float f0 = __uint_as_float((uint32_t)v0);
        float f1 = __uint_as_float((uint32_t)v1);
        {   // fp16 pair into padded chunk layout (p0,p1 are in the same chunk)
            __half2 hh = __floats2half2_rn(f0, f1);
            int chunk = p0 >> 7, loc = p0 & 127;
            *(__half2*)(h_s + chunk * 136 + loc) = hh;
        }
        if ((tid >> 4) == g) {   // fp32 state copy for our own 32 columns
            h32_s[(tid & 15) * 2]     = f0;
            h32_s[(tid & 15) * 2 + 1] = f1;
        }
        __syncthreads();   // h_s(t), h32_s(t) complete

        // update-thread preloads (safe until sync#2; writers for t+1 are gated
        // on OUR publish, which happens after sync#2)
        float hold = 0.f, wzv = 0.f, whv = 0.f;
        if (tid < 32) {
            hold = h32_s[tid];
            int j = g * 32 + tid;
            int sb = (t < T_) ? c : (B_ - 1 - c);
            int st = (t < T_) ? t : (t - T_);
            const __half* wrow = WX + (size_t)(sb * T_ + st) * NG_;
            wzv = __half2float(wrow[j]);
            whv = __half2float(wrow[H_ + j]);
        }

        // ---- u = h . U^T  (each thread: 1 row x 128-wide K chunk, fp16 dot2) ----
        float acc = 0.f;
        const uint4* h4 = (const uint4*)(h_s + ck * 136);
#pragma unroll
        for (int q = 0; q < 16; ++q) {
            uint4 hv = h4[q];   // 8 halves
            acc = dot2f(ureg[4 * q + 0], hv.x, acc);
            acc = dot2f(ureg[4 * q + 1], hv.y, acc);
            acc = dot2f(ureg[4 * q + 2], hv.z, acc);
            acc = dot2f(ureg[4 * q + 3], hv.w, acc);
        }
        acc += __shfl_xor(acc, 1);
        acc += __shfl_xor(acc, 2);
        if (ck == 0) u_s[lr] = acc;
        __syncthreads();   // u_s complete; all h_s(t) reads done

        // ---- gate update + publish h_{t+1} ----
        if (tid < 32) {
            int j = g * 32 + tid;
            float uz = u_s[tid], uh = u_s[32 + tid];
            float z = 1.f / (1.f + __expf(-(wzv + uz)));
            float hc = fmaxf(whv + uh, 0.f);
            float hn = z * hold + (1.f - z) * hc;
            uint64_t pk = ((uint64_t)(uint32_t)(t + 1) << 32) | (uint64_t)__float_as_uint(hn);
            __hip_atomic_store(&myb[(size_t)((t + 1) & 1) * 512 + j], pk,
                               __ATOMIC_RELAXED, __HIP_MEMORY_SCOPE_AGENT);
            size_t off;
            if (t < T_) off = ((size_t)(c * T_ + t)) * NG_ + j;                        // forward half
            else        off = ((size_t)((B_ - 1 - c) * T_ + (t - T_))) * NG_ + H_ + j; // backward half
            out_pre[off] = __float2half(hn);
        }
    }
}

// ---------------------------------------------------------------------------
// Phase 3a: LayerNorm over last dim (1024), in place on f16 buffer
// ---------------------------------------------------------------------------
__global__ __launch_bounds__(256) void ln_kernel(__half* __restrict__ buf,
                                                 const float* __restrict__ g,
                                                 const float* __restrict__ b) {
    __shared__ float red[2][4];
    int row = blockIdx.x, tid = threadIdx.x;
    __half* p = buf + (size_t)row * NG_ + tid * 4;
    uint2 raw = *(const uint2*)p;
    __half2 h01 = *(__half2*)&raw.x, h23 = *(__half2*)&raw.y;
    float2 f01 = __half22float2(h01), f23 = __half22float2(h23);
    float s = f01.x + f01.y + f23.x + f23.y;
    float ss = fmaf(f01.x, f01.x, fmaf(f01.y, f01.y, fmaf(f23.x, f23.x, f23.y * f23.y)));
#pragma unroll
    for (int m = 32; m >= 1; m >>= 1) { s += __shfl_xor(s, m); ss += __shfl_xor(ss, m); }
    int w = tid >> 6;
    if ((tid & 63) == 0) { red[0][w] = s; red[1][w] = ss; }
    __syncthreads();
    float S = red[0][0] + red[0][1] + red[0][2] + red[0][3];
    float SS = red[1][0] + red[1][1] + red[1][2] + red[1][3];
    float mu = S * (1.f / NG_);
    float var = SS * (1.f / NG_) - mu * mu;
    float rstd = rsqrtf(var + 1e-5f);
    int d = tid * 4;
    float o0 = (f01.x - mu) * rstd * g[d + 0] + b[d + 0];
    float o1 = (f01.y - mu) * rstd * g[d + 1] + b[d + 1];
    float o2 = (f23.x - mu) * rstd * g[d + 2] + b[d + 2];
    float o3 = (f23.y - mu) * rstd * g[d + 3] + b[d + 3];
    __half2 a = __floats2half2_rn(o0, o1), c = __floats2half2_rn(o2, o3);
    uint2 out; out.x = *(uint32_t*)&a; out.y = *(uint32_t*)&c;
    *(uint2*)p = out;
}

// ---------------------------------------------------------------------------
// Phase 3b: projection GEMM: out[m,e] = tanh(LN[m,:] . pjW[e,:] + pjb[e]), fp32 out
// ---------------------------------------------------------------------------
__global__ __launch_bounds__(256) void gemm_proj(
    const __half* __restrict__ Ain, const float* __restrict__ pjW,
    const float* __restrict__ pjb, float* __restrict__ outp)
{
    __shared__ float As[16][132];
    __shared__ float Bs[16][144];
    int tid = threadIdx.x;
    int bm = blockIdx.x >> 3, bn = blockIdx.x & 7;
    int m0 = bm * 128, n0 = bn * 128;
    int tm = tid >> 4, tn = tid & 15;
    float acc[8][8] = {};

    for (int k0 = 0; k0 < 1024; k0 += 16) {
        {
            int row = tid >> 1, hb = (tid & 1) * 8;
            uint4 raw = *(const uint4*)(Ain + (size_t)(m0 + row) * NG_ + k0 + hb);
            const __half2* hp = (const __half2*)&raw;
#pragma unroll
            for (int q = 0; q < 4; ++q) {
                float2 f = __half22float2(hp[q]);
                As[hb + 2 * q][row] = f.x;
                As[hb + 2 * q + 1][row] = f.y;
            }
        }
#pragma unroll
        for (int i = 0; i < 2; ++i) {
            int f = tid * 2 + i;
            int row = f >> 2, c4 = (f & 3) * 4;
            float4 v = *(const float4*)(pjW + (size_t)(n0 + row) * 1024 + k0 + c4);
            int r = swz(row);
            Bs[c4 + 0][r] = v.x; Bs[c4 + 1][r] = v.y;
            Bs[c4 + 2][r] = v.z; Bs[c4 + 3][r] = v.w;
        }
        __syncthreads();
#pragma unroll
        for (int kk = 0; kk < 16; ++kk) {
            float a[8], b[8];
            *(float4*)&a[0] = *(const float4*)&As[kk][tm * 8];
            *(float4*)&a[4] = *(const float4*)&As[kk][tm * 8 + 4];
            *(float4*)&b[0] = *(const float4*)&Bs[kk][swz(tn * 8)];
            *(float4*)&b[4] = *(const float4*)&Bs[kk][swz(tn * 8) + 4];
#pragma unroll
            for (int i = 0; i < 8; ++i)
#pragma unroll
                for (int j = 0; j < 8; ++j)
                    acc[i][j] = fmaf(a[i], b[j], acc[i][j]);
        }
        __syncthreads();
    }

#pragma unroll
    for (int i = 0; i < 8; ++i) {
        size_t rowoff = (size_t)(m0 + tm * 8 + i) * NG_ + n0 + tn * 8;
#pragma unroll
        for (int j = 0; j < 8; ++j) {
            int n = n0 + tn * 8 + j;
            outp[rowoff + j] = tanhf(acc[i][j] + pjb[n]);
        }
    }
}

// ---------------------------------------------------------------------------
extern "C" void kernel_launch(void* const* d_in, const int* in_sizes, int n_in,
                              void* d_out, int out_size, void* d_ws, size_t ws_size,
                              hipStream_t stream) {
    const float* x    = (const float*)d_in[0];
    const int*   xlen = (const int*)  d_in[1];
    const float* Wz   = (const float*)d_in[2];
    const float* bz   = (const float*)d_in[3];
    const float* Wh   = (const float*)d_in[4];
    const float* bh   = (const float*)d_in[5];
    const float* U    = (const float*)d_in[6];
    const float* zg   = (const float*)d_in[7];
    const float* zb   = (const float*)d_in[8];
    const float* zm   = (const float*)d_in[9];
    const float* zv   = (const float*)d_in[10];
    const float* hg   = (const float*)d_in[11];
    const float* hb   = (const float*)d_in[12];
    const float* hm   = (const float*)d_in[13];
    const float* hv   = (const float*)d_in[14];
    const float* lng  = (const float*)d_in[15];
    const float* lnb  = (const float*)d_in[16];
    const float* pjW  = (const float*)d_in[17];
    const float* pjb  = (const float*)d_in[18];

    char* ws = (char*)d_ws;
    __half*   WX      = (__half*)(ws + WX_OFF);
    __half*   out_pre = (__half*)(ws + OUTPRE_OFF);
    uint64_t* htag    = (uint64_t*)(ws + HTAG_OFF);
    float* out = (float*)d_out;

    init_kernel<<<64, 256, 0, stream>>>(htag, xlen, out + (size_t)M1_ * NG_);
    gemm_gates<<<1000, 256, 0, stream>>>(x, Wz, Wh, bz, bh, zg, zb, zm, zv,
                                         hg, hb, hm, hv, WX);
    recur_kernel<<<256, 256, 0, stream>>>(WX, U, htag, out_pre);
    ln_kernel<<<M1_, 256, 0, stream>>>(out_pre, lng, lnb);
    gemm_proj<<<1000, 256, 0, stream>>>(out_pre, pjW, pjb, out);
}